// Round 6
// baseline (1481.258 us; speedup 1.0000x reference)
//
#include <hip/hip_runtime.h>
#include <math.h>

#define DEVFN __device__ __forceinline__

namespace {

typedef __bf16 bf16x8 __attribute__((ext_vector_type(8)));
typedef float  f32x4  __attribute__((ext_vector_type(4)));

constexpr int T = 28, B = 16384, X = 28, H = 100, Z = 16;
constexpr int ROWS = 16;           // one M-tile per block -> grid 1024
constexpr int NTH  = 256;          // 4 waves -> target 3 blocks/CU = 12 waves/CU
constexpr int ST   = 104;          // bf16 LDS stride; kc=3 junk cols (>=100) hit zero weights
constexpr int HBUF = ROWS*ST + 24; // tail pad: row-15 kc=3 frag overrun stays in-buffer (zeroed)
constexpr int XST  = 40;           // stride for Z rows
constexpr float KEPS = 1e-10f;

// ---- weight-fragment table (1 frag = 16x32 B-tile = 64 lanes x 16B = 1024B) ----
constexpr int FB_PX   = 0;    // 7   KT=1
constexpr int FB_HE   = 7;    // 56  KT=8 (concat px|h)
constexpr int FB_EMU  = 63;   // 4   KT=4
constexpr int FB_ESIG = 67;   // 4
constexpr int FB_HP   = 71;   // 28  KT=4
constexpr int FB_PMU  = 99;   // 4
constexpr int FB_PSIG = 103;  // 4
constexpr int FB_PZ   = 107;  // 7   KT=1
constexpr int FB_HD1  = 114;  // 56  KT=8 (concat pz|h)
constexpr int FB_HD2  = 170;  // 28  KT=4
constexpr int FB_PRB  = 198;  // 8   KT=4 (Nt=2)
constexpr int FB_GIR  = 206;  // 56  KT=8 (concat pz|px)
constexpr int FB_GIU  = 262;  // 56
constexpr int FB_GIN  = 318;  // 56
constexpr int FB_GHR  = 374;  // 28  KT=4
constexpr int FB_GHU  = 402;  // 28
constexpr int FB_GHN  = 430;  // 28
constexpr int NFRAG   = 458;  // 469 KB in d_ws

struct Params {
  const float *x,*eps,*Wpx,*bpx,*Wpz,*bpz,*Wp1,*bp1,*Wp_mu,*bp_mu,*Wp_sig,*bp_sig,
              *We1,*be1,*We_mu,*be_mu,*We_sig,*be_sig,*Wd1,*bd1,*Wd2,*bd2,*Wd3,*bd3,
              *Wih,*Whh,*bih,*bhh;
  float *out;
};

DEVFN float fsigmoid(float v){ return 1.f/(1.f+__expf(-v)); }
DEVFN float fsoftplus(float v){ return (v > 15.f) ? v : log1pf(__expf(v)); }
DEVFN float ftanh(float v){
  v = fminf(fmaxf(v,-15.f),15.f);
  float e = __expf(2.f*v);
  return (e-1.f)/(e+1.f);
}

DEVFN f32x4 MFMA(bf16x8 a, bf16x8 b, f32x4 c){
  return __builtin_amdgcn_mfma_f32_16x16x32_bf16(a, b, c, 0, 0, 0);
}

// ---------------- weight prep: fp32 -> bf16 B-fragments in d_ws ----------------
__global__ void prep_kernel(Params P, __bf16* FRW)
{
  const int f = blockIdx.x, l = threadIdx.x;
  const int bases[18] = {FB_PX,FB_HE,FB_EMU,FB_ESIG,FB_HP,FB_PMU,FB_PSIG,FB_PZ,FB_HD1,
                         FB_HD2,FB_PRB,FB_GIR,FB_GIU,FB_GIN,FB_GHR,FB_GHU,FB_GHN,NFRAG};
  int li = 0;
  while (f >= bases[li+1]) ++li;

  const float* W; int KT, N, roff, wstr, vK, mode;
  switch (li) {
    case 0:  W=P.Wpx;    KT=1; N=100; roff=0;   wstr=28;  vK=28;  mode=0; break;
    case 1:  W=P.We1;    KT=8; N=100; roff=0;   wstr=200; vK=100; mode=1; break;
    case 2:  W=P.We_mu;  KT=4; N=16;  roff=0;   wstr=100; vK=100; mode=0; break;
    case 3:  W=P.We_sig; KT=4; N=16;  roff=0;   wstr=100; vK=100; mode=0; break;
    case 4:  W=P.Wp1;    KT=4; N=100; roff=0;   wstr=100; vK=100; mode=0; break;
    case 5:  W=P.Wp_mu;  KT=4; N=16;  roff=0;   wstr=100; vK=100; mode=0; break;
    case 6:  W=P.Wp_sig; KT=4; N=16;  roff=0;   wstr=100; vK=100; mode=0; break;
    case 7:  W=P.Wpz;    KT=1; N=100; roff=0;   wstr=16;  vK=16;  mode=0; break;
    case 8:  W=P.Wd1;    KT=8; N=100; roff=0;   wstr=200; vK=100; mode=1; break;
    case 9:  W=P.Wd2;    KT=4; N=100; roff=0;   wstr=100; vK=100; mode=0; break;
    case 10: W=P.Wd3;    KT=4; N=28;  roff=0;   wstr=100; vK=100; mode=0; break;
    case 11: W=P.Wih;    KT=8; N=100; roff=0;   wstr=200; vK=100; mode=1; break;
    case 12: W=P.Wih;    KT=8; N=100; roff=100; wstr=200; vK=100; mode=1; break;
    case 13: W=P.Wih;    KT=8; N=100; roff=200; wstr=200; vK=100; mode=1; break;
    case 14: W=P.Whh;    KT=4; N=100; roff=0;   wstr=100; vK=100; mode=0; break;
    case 15: W=P.Whh;    KT=4; N=100; roff=100; wstr=100; vK=100; mode=0; break;
    default: W=P.Whh;    KT=4; N=100; roff=200; wstr=100; vK=100; mode=0; break;
  }
  const int idx = f - bases[li];
  const int nt = idx / KT, kc = idx % KT;
  const int n  = nt*16 + (l & 15);

  bf16x8 v;
  #pragma unroll
  for (int j = 0; j < 8; ++j) {
    int kk  = (mode ? (kc & 3) : kc)*32 + ((l >> 4)*8) + j;
    int col = mode ? ((kc < 4 ? 0 : 100) + kk) : kk;
    float w = (n < N && kk < vK) ? W[(size_t)(roff + n)*wstr + col] : 0.f;
    v[j] = (__bf16)w;
  }
  *((bf16x8*)FRW + (size_t)f*64 + l) = v;
}

// ---------------- main kernel helpers (single M-tile) ----------------
template<int NC>
DEVFN void load_afrags(bf16x8 (&af)[NC], const __bf16* A, int stride, int lane)
{
  const __bf16* p = A + (size_t)(lane & 15)*stride + ((lane >> 4)*8);
  #pragma unroll
  for (int kc = 0; kc < NC; ++kc) af[kc] = *(const bf16x8*)(p + kc*32);
}

// H-output layer: this wave does nt = sw, sw+4, ... ; relu; bf16 dst (stride ST)
template<int KT, int NA>
DEVFN void layerH(const bf16x8 (&af)[NA], const bf16x8* FRbase, const float* bias,
                  __bf16* dst, int sw, int lane)
{
  for (int nt = sw; nt < 7; nt += 4) {
    f32x4 acc = {0.f,0.f,0.f,0.f};
    const bf16x8* wf = FRbase + (size_t)nt*KT*64 + lane;
    #pragma unroll
    for (int kc = 0; kc < KT; ++kc) acc = MFMA(af[kc], wf[kc*64], acc);
    const int col = nt*16 + (lane & 15);
    if (col < H) {
      const float b = bias[col];
      const int rbase = (lane >> 4)*4;
      #pragma unroll
      for (int r = 0; r < 4; ++r)
        dst[(size_t)(rbase + r)*ST + col] = (__bf16)fmaxf(acc[r] + b, 0.f);
    }
  }
}

// K-concat variant of layerH (two 4-frag A arrays)
DEVFN void layerHcat(const bf16x8 (&a0)[4], const bf16x8 (&a1)[4], const bf16x8* FRbase,
                     const float* bias, __bf16* dst, int sw, int lane)
{
  for (int nt = sw; nt < 7; nt += 4) {
    f32x4 acc = {0.f,0.f,0.f,0.f};
    const bf16x8* wf = FRbase + (size_t)nt*8*64 + lane;
    #pragma unroll
    for (int kc = 0; kc < 4; ++kc) acc = MFMA(a0[kc], wf[kc*64], acc);
    #pragma unroll
    for (int kc = 0; kc < 4; ++kc) acc = MFMA(a1[kc], wf[(4+kc)*64], acc);
    const int col = nt*16 + (lane & 15);
    if (col < H) {
      const float b = bias[col];
      const int rbase = (lane >> 4)*4;
      #pragma unroll
      for (int r = 0; r < 4; ++r)
        dst[(size_t)(rbase + r)*ST + col] = (__bf16)fmaxf(acc[r] + b, 0.f);
    }
  }
}

template<int KT>
DEVFN f32x4 head4(const bf16x8 (&af)[KT], const bf16x8* FRbase, int lane)
{
  f32x4 acc = {0.f,0.f,0.f,0.f};
  #pragma unroll
  for (int kc = 0; kc < KT; ++kc) acc = MFMA(af[kc], FRbase[kc*64 + lane], acc);
  return acc;
}

__global__ __launch_bounds__(NTH, 3) void vrnn_kernel(Params P, const __bf16* FRW)
{
  __shared__ alignas(16) __bf16 sPX[HBUF];
  __shared__ alignas(16) __bf16 sPZ[HBUF];
  __shared__ alignas(16) __bf16 sA [HBUF];   // he -> hd1
  __shared__ alignas(16) __bf16 sB [HBUF];   // hp -> hd2
  __shared__ alignas(16) __bf16 sH [HBUF];   // single-buffered h
  __shared__ alignas(16) __bf16 sZ [ROWS*XST];
  __shared__ float sred[8];

  const bf16x8* FR = (const bf16x8*)FRW;
  const int tid  = threadIdx.x;
  const int lane = tid & 63;
  const int wv   = tid >> 6;       // 0..3
  const int gr0  = blockIdx.x * ROWS;

  // zero-init ALL LDS (junk cols must be finite: junk * zero-weight = 0)
  for (int i = tid; i < HBUF; i += NTH) {
    sPX[i]=(__bf16)0.f; sPZ[i]=(__bf16)0.f; sA[i]=(__bf16)0.f; sB[i]=(__bf16)0.f; sH[i]=(__bf16)0.f;
  }
  for (int i = tid; i < ROWS*XST; i += NTH) sZ[i]=(__bf16)0.f;
  __syncthreads();

  float kl = 0.f, nll = 0.f;

  for (int t = 0; t < T; ++t) {
    // ---- P1: px = relu(x Wpx^T + b) (x A-frag from global) ; hp = relu(h Wp1^T + b) -> sB
    {
      const int m = lane & 15, quad = lane >> 4;
      const float* xr = P.x + ((size_t)t*B + gr0 + m)*X + quad*8;
      float4 fa = *(const float4*)xr;
      float4 fb = make_float4(0.f,0.f,0.f,0.f);
      if (quad < 3) fb = *(const float4*)(xr + 4);
      bf16x8 ax;
      ax[0]=(__bf16)fa.x; ax[1]=(__bf16)fa.y; ax[2]=(__bf16)fa.z; ax[3]=(__bf16)fa.w;
      ax[4]=(__bf16)fb.x; ax[5]=(__bf16)fb.y; ax[6]=(__bf16)fb.z; ax[7]=(__bf16)fb.w;
      bf16x8 axA[1] = {ax};
      layerH<1,1>(axA, FR + (size_t)FB_PX*64, P.bpx, sPX, wv, lane);
      bf16x8 ah[4]; load_afrags(ah, sH, ST, lane);
      layerH<4,4>(ah, FR + (size_t)FB_HP*64, P.bp1, sB, 3 - wv, lane);
    }
    __syncthreads();   // B1

    // ---- P2: he = relu([px|h] We1^T + b) -> sA
    {
      bf16x8 a0[4]; load_afrags(a0, sPX, ST, lane);
      bf16x8 a1[4]; load_afrags(a1, sH,  ST, lane);
      layerHcat(a0, a1, FR + (size_t)FB_HE*64, P.be1, sA, wv, lane);
    }
    __syncthreads();   // B2

    // ---- P3 (no barrier): ALL 4 waves compute all 4 Z-heads; z dup-written to sZ;
    //      KL split by register index (wave w accumulates r==w)
    {
      bf16x8 a1[4]; load_afrags(a1, sA, ST, lane);
      bf16x8 a2[4]; load_afrags(a2, sB, ST, lane);
      f32x4 emu = head4(a1, FR + (size_t)FB_EMU*64,  lane);
      f32x4 esg = head4(a1, FR + (size_t)FB_ESIG*64, lane);
      f32x4 pmu = head4(a2, FR + (size_t)FB_PMU*64,  lane);
      f32x4 psg = head4(a2, FR + (size_t)FB_PSIG*64, lane);
      const int zi = lane & 15;
      const int rbase = (lane >> 4)*4;
      const float bem = P.be_mu[zi], bes = P.be_sig[zi];
      const float bpm = P.bp_mu[zi], bps = P.bp_sig[zi];
      #pragma unroll
      for (int r = 0; r < 4; ++r) {
        float em = emu[r] + bem;
        float es = fsoftplus(esg[r] + bes);
        float ev = P.eps[((size_t)t*B + gr0 + rbase + r)*Z + zi];
        sZ[(rbase + r)*XST + zi] = (__bf16)(em + sqrtf(es)*ev);   // dup write: identical values
        if (r == wv) {   // each wave accumulates a quarter of the KL terms
          float pm = pmu[r] + bpm;
          float ps = fsoftplus(psg[r] + bps) + KEPS;
          float dm = em - pm;
          kl += 0.5f*(2.f*__logf(ps) - 2.f*__logf(es) + (es*es + dm*dm)/(ps*ps) - 1.f);
        }
      }
    }
    // no barrier: each wave wrote (and reads) every sZ row itself

    // ---- P4: pz = relu(z Wpz^T + b) -> sPZ
    {
      bf16x8 az[1]; load_afrags(az, sZ, XST, lane);
      layerH<1,1>(az, FR + (size_t)FB_PZ*64, P.bpz, sPZ, 3 - wv, lane);
    }
    __syncthreads();   // B4

    // ---- P5: load all A-frags; barrier; hd1 -> sA ; fused GRU -> sH (in place)
    {
      bf16x8 apz[4]; load_afrags(apz, sPZ, ST, lane);
      bf16x8 ah [4]; load_afrags(ah,  sH,  ST, lane);
      bf16x8 apx[4]; load_afrags(apx, sPX, ST, lane);
      __syncthreads(); // B5a: all waves' h/pz/px frags in regs before any sH/sA write

      layerHcat(apz, ah, FR + (size_t)FB_HD1*64, P.bd1, sA, wv, lane);

      for (int c = 3 - wv; c < 7; c += 4) {
        f32x4 gr={0.f,0.f,0.f,0.f}, gu={0.f,0.f,0.f,0.f}, gn={0.f,0.f,0.f,0.f};
        f32x4 hr={0.f,0.f,0.f,0.f}, hu={0.f,0.f,0.f,0.f}, hn={0.f,0.f,0.f,0.f};
        const bf16x8* wr = FR + (size_t)(FB_GIR + c*8)*64 + lane;
        const bf16x8* wu = FR + (size_t)(FB_GIU + c*8)*64 + lane;
        const bf16x8* wn = FR + (size_t)(FB_GIN + c*8)*64 + lane;
        #pragma unroll
        for (int kc = 0; kc < 4; ++kc) {        // gi part 1: pz
          bf16x8 a = apz[kc];
          gr = MFMA(a, wr[kc*64], gr); gu = MFMA(a, wu[kc*64], gu); gn = MFMA(a, wn[kc*64], gn);
        }
        #pragma unroll
        for (int kc = 0; kc < 4; ++kc) {        // gi part 2: px
          bf16x8 a = apx[kc];
          gr = MFMA(a, wr[(4+kc)*64], gr); gu = MFMA(a, wu[(4+kc)*64], gu); gn = MFMA(a, wn[(4+kc)*64], gn);
        }
        const bf16x8* vr = FR + (size_t)(FB_GHR + c*4)*64 + lane;
        const bf16x8* vu = FR + (size_t)(FB_GHU + c*4)*64 + lane;
        const bf16x8* vn = FR + (size_t)(FB_GHN + c*4)*64 + lane;
        #pragma unroll
        for (int kc = 0; kc < 4; ++kc) {        // gh: h
          bf16x8 a = ah[kc];
          hr = MFMA(a, vr[kc*64], hr); hu = MFMA(a, vu[kc*64], hu); hn = MFMA(a, vn[kc*64], hn);
        }
        const int n = c*16 + (lane & 15);
        if (n < H) {
          const float bir=P.bih[n], biu=P.bih[n+H], bin=P.bih[n+2*H];
          const float bhr=P.bhh[n], bhu=P.bhh[n+H], bhn=P.bhh[n+2*H];
          const int rbase = (lane >> 4)*4;
          #pragma unroll
          for (int r = 0; r < 4; ++r) {
            float rr = fsigmoid(gr[r] + bir + hr[r] + bhr);
            float uu = fsigmoid(gu[r] + biu + hu[r] + bhu);
            float nn = ftanh(gn[r] + bin + rr*(hn[r] + bhn));
            float ho = (float)sH[(size_t)(rbase+r)*ST + n];   // own (row,col): cols partition by wave
            sH[(size_t)(rbase+r)*ST + n] = (__bf16)((1.f-uu)*nn + uu*ho);
          }
        }
      }
    }
    __syncthreads();   // B5b

    // ---- P6: hd2 = relu(hd1 Wd2^T + b) : sA -> sB
    {
      bf16x8 af[4]; load_afrags(af, sA, ST, lane);
      layerH<4,4>(af, FR + (size_t)FB_HD2*64, P.bd2, sB, wv, lane);
    }
    __syncthreads();   // B6

    // ---- P7: logits v = hd2 Wd3^T + b ; NLL via log-sigmoid identity (waves 0-1)
    if (wv < 2) {
      bf16x8 af[4]; load_afrags(af, sB, ST, lane);
      f32x4 acc = head4(af, FR + (size_t)(FB_PRB + wv*4)*64, lane);
      const int n = wv*16 + (lane & 15);
      if (n < X) {
        const float b = P.bd3[n];
        const int rbase = (lane >> 4)*4;
        #pragma unroll
        for (int r = 0; r < 4; ++r) {
          float v  = acc[r] + b;
          float xv = P.x[((size_t)t*B + gr0 + rbase + r)*X + n];
          // -x log(sig(v)) - (1-x) log(1-sig(v)) = max(-v,0)+log1p(e^-|v|) + (1-x)*v
          nll += fmaxf(-v, 0.f) + log1pf(__expf(-fabsf(v))) + (1.f - xv)*v;
        }
      }
    }
    __syncthreads();   // B7 (protects sPX/sB overwrite next step)
  } // t

  // ---- reduce kl/nll: wave shuffle -> LDS -> one atomicAdd per block
  for (int off = 32; off > 0; off >>= 1) {
    kl  += __shfl_down(kl,  off);
    nll += __shfl_down(nll, off);
  }
  if (lane == 0) { sred[wv] = kl; sred[4 + wv] = nll; }
  __syncthreads();
  if (tid == 0) {
    atomicAdd(&P.out[0], (sred[0]+sred[1]+sred[2]+sred[3]) * (1.f/(float)B));
    atomicAdd(&P.out[1], (sred[4]+sred[5]+sred[6]+sred[7]) * (1.f/(float)B));
  }
}

} // namespace

extern "C" void kernel_launch(void* const* d_in, const int* in_sizes, int n_in,
                              void* d_out, int out_size, void* d_ws, size_t ws_size,
                              hipStream_t stream)
{
  Params p;
  const float* const* f = (const float* const*)d_in;
  p.x=f[0];    p.eps=f[1];
  p.Wpx=f[2];  p.bpx=f[3];   p.Wpz=f[4];   p.bpz=f[5];
  p.Wp1=f[6];  p.bp1=f[7];   p.Wp_mu=f[8]; p.bp_mu=f[9];
  p.Wp_sig=f[10]; p.bp_sig=f[11];
  p.We1=f[12]; p.be1=f[13];  p.We_mu=f[14]; p.be_mu=f[15];
  p.We_sig=f[16]; p.be_sig=f[17];
  p.Wd1=f[18]; p.bd1=f[19];  p.Wd2=f[20];  p.bd2=f[21];
  p.Wd3=f[22]; p.bd3=f[23];
  p.Wih=f[24]; p.Whh=f[25];  p.bih=f[26];  p.bhh=f[27];
  p.out = (float*)d_out;

  hipMemsetAsync(d_out, 0, 2*sizeof(float), stream);
  prep_kernel<<<dim3(NFRAG), dim3(64), 0, stream>>>(p, (__bf16*)d_ws);
  vrnn_kernel<<<dim3(B/ROWS), dim3(NTH), 0, stream>>>(p, (const __bf16*)d_ws);
}

// Round 7
// 1083.625 us; speedup vs baseline: 1.3669x; 1.3669x over previous
//
#include <hip/hip_runtime.h>
#include <math.h>

#define DEVFN __device__ __forceinline__

namespace {

typedef __bf16 bf16x8 __attribute__((ext_vector_type(8)));
typedef float  f32x4  __attribute__((ext_vector_type(4)));

constexpr int T = 28, B = 16384, X = 28, H = 100, Z = 16;
constexpr int ROWS = 16;           // one M-tile per block -> grid 1024, 4 blocks/CU
constexpr int NTH  = 128;          // 2 waves (proven no-spill shape, R5)
constexpr int ST   = 104;          // bf16 LDS stride; cols 100..103 = bias-one/zero, overrun cols hit zero weights
constexpr int HBUF = ROWS*ST + 24; // tail pad: row-15 kc=3 frag overrun stays in-buffer (zeroed)
constexpr int XST  = 40;           // stride for Z rows
constexpr float KEPS = 1e-10f;

// ---- weight-fragment table (1 frag = 16x32 B-tile = 64 lanes x 16B = 1024B) ----
constexpr int FB_PX   = 0;    // 7   KT=1
constexpr int FB_HE   = 7;    // 56  KT=8 (concat px|h)
constexpr int FB_EMU  = 63;   // 4   KT=4
constexpr int FB_ESIG = 67;   // 4
constexpr int FB_HP   = 71;   // 28  KT=4
constexpr int FB_PMU  = 99;   // 4
constexpr int FB_PSIG = 103;  // 4
constexpr int FB_PZ   = 107;  // 7   KT=1
constexpr int FB_HD1  = 114;  // 56  KT=8 (concat pz|h)
constexpr int FB_HD2  = 170;  // 28  KT=4
constexpr int FB_PRB  = 198;  // 8   KT=4 (Nt=2)
constexpr int FB_GIR  = 206;  // 56  KT=8 (concat pz|px)
constexpr int FB_GIU  = 262;  // 56
constexpr int FB_GIN  = 318;  // 56
constexpr int FB_GHR  = 374;  // 28  KT=4
constexpr int FB_GHU  = 402;  // 28
constexpr int FB_GHN  = 430;  // 28
constexpr int NFRAG   = 458;  // 469 KB in d_ws

struct Params {
  const float *x,*eps,*Wpx,*bpx,*Wpz,*bpz,*Wp1,*bp1,*Wp_mu,*bp_mu,*Wp_sig,*bp_sig,
              *We1,*be1,*We_mu,*be_mu,*We_sig,*be_sig,*Wd1,*bd1,*Wd2,*bd2,*Wd3,*bd3,
              *Wih,*Whh,*bih,*bhh;
  float *out;
};

DEVFN float frcp(float x){ return __builtin_amdgcn_rcpf(x); }
DEVFN float fsigmoid(float v){ return frcp(1.f + __expf(-v)); }
DEVFN float ftanh(float v){
  float t = __expf(-2.f*fabsf(v));           // (0,1], no overflow
  float r = (1.f - t) * frcp(1.f + t);
  return copysignf(r, v);
}
DEVFN float fsoftplus(float v){
  float sp = (v > 15.f) ? v : __logf(1.f + __expf(v));
  return fmaxf(sp, 1e-6f);                   // log/rcp safety in KL tail
}

DEVFN f32x4 MFMA(bf16x8 a, bf16x8 b, f32x4 c){
  return __builtin_amdgcn_mfma_f32_16x16x32_bf16(a, b, c, 0, 0, 0);
}

// ---------------- weight prep: fp32 -> bf16 B-fragments, biases folded into K-pad slot ----------------
__global__ void prep_kernel(Params P, __bf16* FRW)
{
  const int f = blockIdx.x, l = threadIdx.x;
  const int bases[18] = {FB_PX,FB_HE,FB_EMU,FB_ESIG,FB_HP,FB_PMU,FB_PSIG,FB_PZ,FB_HD1,
                         FB_HD2,FB_PRB,FB_GIR,FB_GIU,FB_GIN,FB_GHR,FB_GHU,FB_GHN,NFRAG};
  int li = 0;
  while (f >= bases[li+1]) ++li;

  const float* W; const float* Bv; int KT, N, roff, wstr, vK, mode;
  switch (li) {
    case 0:  W=P.Wpx;    Bv=P.bpx;    KT=1; N=100; roff=0;   wstr=28;  vK=28;  mode=0; break;
    case 1:  W=P.We1;    Bv=P.be1;    KT=8; N=100; roff=0;   wstr=200; vK=100; mode=1; break;
    case 2:  W=P.We_mu;  Bv=P.be_mu;  KT=4; N=16;  roff=0;   wstr=100; vK=100; mode=0; break;
    case 3:  W=P.We_sig; Bv=P.be_sig; KT=4; N=16;  roff=0;   wstr=100; vK=100; mode=0; break;
    case 4:  W=P.Wp1;    Bv=P.bp1;    KT=4; N=100; roff=0;   wstr=100; vK=100; mode=0; break;
    case 5:  W=P.Wp_mu;  Bv=P.bp_mu;  KT=4; N=16;  roff=0;   wstr=100; vK=100; mode=0; break;
    case 6:  W=P.Wp_sig; Bv=P.bp_sig; KT=4; N=16;  roff=0;   wstr=100; vK=100; mode=0; break;
    case 7:  W=P.Wpz;    Bv=P.bpz;    KT=1; N=100; roff=0;   wstr=16;  vK=16;  mode=0; break;
    case 8:  W=P.Wd1;    Bv=P.bd1;    KT=8; N=100; roff=0;   wstr=200; vK=100; mode=1; break;
    case 9:  W=P.Wd2;    Bv=P.bd2;    KT=4; N=100; roff=0;   wstr=100; vK=100; mode=0; break;
    case 10: W=P.Wd3;    Bv=P.bd3;    KT=4; N=28;  roff=0;   wstr=100; vK=100; mode=0; break;
    case 11: W=P.Wih;    Bv=P.bih;    KT=8; N=100; roff=0;   wstr=200; vK=100; mode=1; break;
    case 12: W=P.Wih;    Bv=P.bih;    KT=8; N=100; roff=100; wstr=200; vK=100; mode=1; break;
    case 13: W=P.Wih;    Bv=P.bih;    KT=8; N=100; roff=200; wstr=200; vK=100; mode=1; break;
    case 14: W=P.Whh;    Bv=P.bhh;    KT=4; N=100; roff=0;   wstr=100; vK=100; mode=0; break;
    case 15: W=P.Whh;    Bv=P.bhh;    KT=4; N=100; roff=100; wstr=100; vK=100; mode=0; break;
    default: W=P.Whh;    Bv=P.bhh;    KT=4; N=100; roff=200; wstr=100; vK=100; mode=0; break;
  }
  const int idx = f - bases[li];
  const int nt = idx / KT, kc = idx % KT;
  const int n  = nt*16 + (l & 15);

  bf16x8 v;
  #pragma unroll
  for (int j = 0; j < 8; ++j) {
    int kk  = (mode ? (kc & 3) : kc)*32 + ((l >> 4)*8) + j;
    float w = 0.f;
    if (n < N) {
      if (mode == 0) {
        if (kk < vK)       w = W[(size_t)(roff + n)*wstr + kk];
        else if (kk == vK) w = Bv[roff + n];                      // bias in K-pad slot
      } else {
        int col = (kc < 4 ? 0 : 100) + kk;
        if (kk < 100)                    w = W[(size_t)(roff + n)*wstr + col];
        else if (kc < 4 && kk == 100)    w = Bv[roff + n];        // bias in segment-0 pad slot
      }
    }
    v[j] = (__bf16)w;
  }
  *((bf16x8*)FRW + (size_t)f*64 + l) = v;
}

// ---------------- main kernel helpers (single M-tile) ----------------
template<int NC>
DEVFN void load_afrags(bf16x8 (&af)[NC], const __bf16* A, int stride, int lane)
{
  const __bf16* p = A + (size_t)(lane & 15)*stride + ((lane >> 4)*8);
  #pragma unroll
  for (int kc = 0; kc < NC; ++kc) af[kc] = *(const bf16x8*)(p + kc*32);
}

// H-output layer: wave does nt = sw, sw+2, sw+4, sw+6 (guarded); relu; bias pre-folded
template<int KT, int NA>
DEVFN void layerH(const bf16x8 (&af)[NA], const bf16x8* FRbase, __bf16* dst, int sw, int lane)
{
  #pragma unroll
  for (int i = 0; i < 4; ++i) {
    const int nt = sw + 2*i;
    if (nt < 7) {
      f32x4 acc = {0.f,0.f,0.f,0.f};
      const bf16x8* wf = FRbase + (size_t)nt*KT*64 + lane;
      #pragma unroll
      for (int kc = 0; kc < KT; ++kc) acc = MFMA(af[kc], wf[kc*64], acc);
      const int col = nt*16 + (lane & 15);
      if (col < H) {
        const int rbase = (lane >> 4)*4;
        #pragma unroll
        for (int r = 0; r < 4; ++r)
          dst[(size_t)(rbase + r)*ST + col] = (__bf16)fmaxf(acc[r], 0.f);
      }
    }
  }
}

// K-concat variant: two independent 4-deep MFMA chains per tile
DEVFN void layerHcat(const bf16x8 (&a0)[4], const bf16x8 (&a1)[4], const bf16x8* FRbase,
                     __bf16* dst, int sw, int lane)
{
  #pragma unroll
  for (int i = 0; i < 4; ++i) {
    const int nt = sw + 2*i;
    if (nt < 7) {
      f32x4 accA = {0.f,0.f,0.f,0.f}, accB = {0.f,0.f,0.f,0.f};
      const bf16x8* wf = FRbase + (size_t)nt*8*64 + lane;
      #pragma unroll
      for (int kc = 0; kc < 4; ++kc) accA = MFMA(a0[kc], wf[kc*64], accA);
      #pragma unroll
      for (int kc = 0; kc < 4; ++kc) accB = MFMA(a1[kc], wf[(4+kc)*64], accB);
      const int col = nt*16 + (lane & 15);
      if (col < H) {
        const int rbase = (lane >> 4)*4;
        #pragma unroll
        for (int r = 0; r < 4; ++r)
          dst[(size_t)(rbase + r)*ST + col] = (__bf16)fmaxf(accA[r] + accB[r], 0.f);
      }
    }
  }
}

template<int KT>
DEVFN f32x4 head4(const bf16x8 (&af)[KT], const bf16x8* FRbase, int lane)
{
  f32x4 acc = {0.f,0.f,0.f,0.f};
  #pragma unroll
  for (int kc = 0; kc < KT; ++kc) acc = MFMA(af[kc], FRbase[kc*64 + lane], acc);
  return acc;
}

__global__ __launch_bounds__(NTH, 2) void vrnn_kernel(Params P, const __bf16* FRW)
{
  __shared__ alignas(16) __bf16 sPX[HBUF];
  __shared__ alignas(16) __bf16 sPZ[HBUF];
  __shared__ alignas(16) __bf16 sA [HBUF];   // he -> hd1
  __shared__ alignas(16) __bf16 sB [HBUF];   // hp -> hd2
  __shared__ alignas(16) __bf16 sH [HBUF];   // single-buffered h
  __shared__ alignas(16) __bf16 sZ [ROWS*XST];
  __shared__ float sred[4];

  const bf16x8* FR = (const bf16x8*)FRW;
  const int tid  = threadIdx.x;
  const int lane = tid & 63;
  const int wv   = tid >> 6;       // 0 or 1
  const int gr0  = blockIdx.x * ROWS;

  // zero-init ALL LDS, then plant bias-activation 1.0 at the K-pad column.
  for (int i = tid; i < HBUF; i += NTH) {
    sPX[i]=(__bf16)0.f; sPZ[i]=(__bf16)0.f; sA[i]=(__bf16)0.f; sB[i]=(__bf16)0.f; sH[i]=(__bf16)0.f;
  }
  for (int i = tid; i < ROWS*XST; i += NTH) sZ[i]=(__bf16)0.f;
  __syncthreads();
  if (tid < ROWS) {
    sPX[tid*ST+100]=(__bf16)1.f; sPZ[tid*ST+100]=(__bf16)1.f; sA[tid*ST+100]=(__bf16)1.f;
    sB [tid*ST+100]=(__bf16)1.f; sH [tid*ST+100]=(__bf16)1.f; sZ[tid*XST+16]=(__bf16)1.f;
  }
  __syncthreads();

  float kl = 0.f, nll = 0.f;

  for (int t = 0; t < T; ++t) {
    // ---- P1: px = relu(x Wpx^T + b) (x A-frag from global, bias-one at k=28) ; hp -> sB
    {
      const int m = lane & 15, quad = lane >> 4;
      const float* xr = P.x + ((size_t)t*B + gr0 + m)*X + quad*8;
      float4 fa = *(const float4*)xr;
      float4 fb = make_float4(0.f,0.f,0.f,0.f);
      if (quad < 3) fb = *(const float4*)(xr + 4);
      bf16x8 ax;
      ax[0]=(__bf16)fa.x; ax[1]=(__bf16)fa.y; ax[2]=(__bf16)fa.z; ax[3]=(__bf16)fa.w;
      ax[4]=(__bf16)fb.x; ax[5]=(__bf16)fb.y; ax[6]=(__bf16)fb.z; ax[7]=(__bf16)fb.w;
      if (quad == 3) ax[4] = (__bf16)1.f;    // k=28 bias slot
      bf16x8 axA[1] = {ax};
      layerH<1,1>(axA, FR + (size_t)FB_PX*64, sPX, wv, lane);
      bf16x8 ah[4]; load_afrags(ah, sH, ST, lane);
      layerH<4,4>(ah, FR + (size_t)FB_HP*64, sB, wv ^ 1, lane);
    }
    __syncthreads();   // B1

    // ---- P2: he = relu([px|h] We1^T + b) -> sA
    {
      bf16x8 a0[4]; load_afrags(a0, sPX, ST, lane);
      bf16x8 a1[4]; load_afrags(a1, sH,  ST, lane);
      layerHcat(a0, a1, FR + (size_t)FB_HE*64, sA, wv, lane);
    }
    __syncthreads();   // B2

    // ---- P3 (no barrier): BOTH waves compute all 4 Z-heads; z dup-written; KL split by reg half
    {
      bf16x8 a1[4]; load_afrags(a1, sA, ST, lane);
      bf16x8 a2[4]; load_afrags(a2, sB, ST, lane);
      f32x4 emu = head4(a1, FR + (size_t)FB_EMU*64,  lane);
      f32x4 esg = head4(a1, FR + (size_t)FB_ESIG*64, lane);
      f32x4 pmu = head4(a2, FR + (size_t)FB_PMU*64,  lane);
      f32x4 psg = head4(a2, FR + (size_t)FB_PSIG*64, lane);
      const int zi = lane & 15;
      const int rbase = (lane >> 4)*4;
      #pragma unroll
      for (int r = 0; r < 4; ++r) {
        float em = emu[r];
        float es = fsoftplus(esg[r]);
        float ev = P.eps[((size_t)t*B + gr0 + rbase + r)*Z + zi];
        sZ[(rbase + r)*XST + zi] = (__bf16)(em + __builtin_amdgcn_sqrtf(es)*ev);  // dup write
        if ((r >> 1) == wv) {   // each wave accumulates half the KL terms
          float ps = fsoftplus(psg[r]) + KEPS;
          float dm = em - pmu[r];
          float rps = frcp(ps);
          kl += 0.5f*(2.f*__logf(ps*frcp(es)) + (es*es + dm*dm)*(rps*rps) - 1.f);
        }
      }
    }
    // no barrier: each wave reads only its own sZ writes below

    // ---- P4: pz = relu(z Wpz^T + b) -> sPZ  (bias-one at z col 16)
    {
      bf16x8 az[1]; load_afrags(az, sZ, XST, lane);
      layerH<1,1>(az, FR + (size_t)FB_PZ*64, sPZ, wv ^ 1, lane);
    }
    __syncthreads();   // B4

    // ---- P5: load all A-frags; barrier; hd1 -> sA ; fused GRU -> sH (in place)
    {
      bf16x8 apz[4]; load_afrags(apz, sPZ, ST, lane);
      bf16x8 ah [4]; load_afrags(ah,  sH,  ST, lane);
      bf16x8 apx[4]; load_afrags(apx, sPX, ST, lane);
      __syncthreads(); // B5a: both waves' h/pz/px frags in regs before any sH/sA write

      layerHcat(apz, ah, FR + (size_t)FB_HD1*64, sA, wv, lane);

      #pragma unroll 2
      for (int c = (wv ^ 1); c < 7; c += 2) {
        f32x4 gr={0.f,0.f,0.f,0.f}, gu={0.f,0.f,0.f,0.f}, gn={0.f,0.f,0.f,0.f};
        f32x4 hr={0.f,0.f,0.f,0.f}, hu={0.f,0.f,0.f,0.f}, hn={0.f,0.f,0.f,0.f};
        const bf16x8* wr = FR + (size_t)(FB_GIR + c*8)*64 + lane;
        const bf16x8* wu = FR + (size_t)(FB_GIU + c*8)*64 + lane;
        const bf16x8* wn = FR + (size_t)(FB_GIN + c*8)*64 + lane;
        #pragma unroll
        for (int kc = 0; kc < 4; ++kc) {        // gi part 1: pz (bih folded here)
          bf16x8 a = apz[kc];
          gr = MFMA(a, wr[kc*64], gr); gu = MFMA(a, wu[kc*64], gu); gn = MFMA(a, wn[kc*64], gn);
        }
        #pragma unroll
        for (int kc = 0; kc < 4; ++kc) {        // gi part 2: px
          bf16x8 a = apx[kc];
          gr = MFMA(a, wr[(4+kc)*64], gr); gu = MFMA(a, wu[(4+kc)*64], gu); gn = MFMA(a, wn[(4+kc)*64], gn);
        }
        const bf16x8* vr = FR + (size_t)(FB_GHR + c*4)*64 + lane;
        const bf16x8* vu = FR + (size_t)(FB_GHU + c*4)*64 + lane;
        const bf16x8* vn = FR + (size_t)(FB_GHN + c*4)*64 + lane;
        #pragma unroll
        for (int kc = 0; kc < 4; ++kc) {        // gh: h (bhh folded here)
          bf16x8 a = ah[kc];
          hr = MFMA(a, vr[kc*64], hr); hu = MFMA(a, vu[kc*64], hu); hn = MFMA(a, vn[kc*64], hn);
        }
        const int n = c*16 + (lane & 15);
        if (n < H) {
          const int rbase = (lane >> 4)*4;
          #pragma unroll
          for (int r = 0; r < 4; ++r) {
            float rr = fsigmoid(gr[r] + hr[r]);
            float uu = fsigmoid(gu[r] + hu[r]);
            float nn = ftanh(gn[r] + rr*hn[r]);
            float ho = (float)sH[(size_t)(rbase+r)*ST + n];   // own (row,col): exclusive
            sH[(size_t)(rbase+r)*ST + n] = (__bf16)((1.f-uu)*nn + uu*ho);
          }
        }
      }
    }
    __syncthreads();   // B5b

    // ---- P6: hd2 = relu(hd1 Wd2^T + b) : sA -> sB
    {
      bf16x8 af[4]; load_afrags(af, sA, ST, lane);
      layerH<4,4>(af, FR + (size_t)FB_HD2*64, sB, wv, lane);
    }
    __syncthreads();   // B6

    // ---- P7: logits v = hd2 Wd3^T + b ; NLL via log-sigmoid identity (wave wv does tile wv)
    {
      bf16x8 af[4]; load_afrags(af, sB, ST, lane);
      f32x4 acc = head4(af, FR + (size_t)(FB_PRB + wv*4)*64, lane);
      const int n = wv*16 + (lane & 15);
      if (n < X) {
        const int rbase = (lane >> 4)*4;
        #pragma unroll
        for (int r = 0; r < 4; ++r) {
          float v  = acc[r];
          float xv = P.x[((size_t)t*B + gr0 + rbase + r)*X + n];
          nll += fmaxf(-v, 0.f) + __logf(1.f + __expf(-fabsf(v))) + (1.f - xv)*v;
        }
      }
    }
    __syncthreads();   // B7 (protects sPX/sB overwrite next step)
  } // t

  // ---- reduce kl/nll: wave shuffle -> LDS -> one atomicAdd per block
  for (int off = 32; off > 0; off >>= 1) {
    kl  += __shfl_down(kl,  off);
    nll += __shfl_down(nll, off);
  }
  if (lane == 0) { sred[wv] = kl; sred[2 + wv] = nll; }
  __syncthreads();
  if (tid == 0) {
    atomicAdd(&P.out[0], (sred[0] + sred[1]) * (1.f/(float)B));
    atomicAdd(&P.out[1], (sred[2] + sred[3]) * (1.f/(float)B));
  }
}

} // namespace

extern "C" void kernel_launch(void* const* d_in, const int* in_sizes, int n_in,
                              void* d_out, int out_size, void* d_ws, size_t ws_size,
                              hipStream_t stream)
{
  Params p;
  const float* const* f = (const float* const*)d_in;
  p.x=f[0];    p.eps=f[1];
  p.Wpx=f[2];  p.bpx=f[3];   p.Wpz=f[4];   p.bpz=f[5];
  p.Wp1=f[6];  p.bp1=f[7];   p.Wp_mu=f[8]; p.bp_mu=f[9];
  p.Wp_sig=f[10]; p.bp_sig=f[11];
  p.We1=f[12]; p.be1=f[13];  p.We_mu=f[14]; p.be_mu=f[15];
  p.We_sig=f[16]; p.be_sig=f[17];
  p.Wd1=f[18]; p.bd1=f[19];  p.Wd2=f[20];  p.bd2=f[21];
  p.Wd3=f[22]; p.bd3=f[23];
  p.Wih=f[24]; p.Whh=f[25];  p.bih=f[26];  p.bhh=f[27];
  p.out = (float*)d_out;

  hipMemsetAsync(d_out, 0, 2*sizeof(float), stream);
  prep_kernel<<<dim3(NFRAG), dim3(64), 0, stream>>>(p, (__bf16*)d_ws);
  vrnn_kernel<<<dim3(B/ROWS), dim3(NTH), 0, stream>>>(p, (const __bf16*)d_ws);
}

// Round 8
// 684.209 us; speedup vs baseline: 2.1649x; 1.5838x over previous
//
#include <hip/hip_runtime.h>
#include <math.h>

#define DEVFN __device__ __forceinline__

namespace {

typedef __bf16 bf16x8 __attribute__((ext_vector_type(8)));
typedef float  f32x4  __attribute__((ext_vector_type(4)));

constexpr int T = 28, B = 16384, X = 28, H = 100, Z = 16;
constexpr int ROWS = 16;           // one M-tile per block -> grid 1024, 4 blocks/CU
constexpr int NTH  = 128;          // 2 waves (proven no-spill shape, R5)
constexpr int ST   = 104;          // bf16 LDS stride; col 100 = bias-one, 101+ zero, overrun cols hit zero weights
constexpr int HBUF = ROWS*ST + 24; // tail pad: row-15 kc=3 frag overrun stays in-buffer (zeroed)
constexpr int XST  = 40;           // stride for Z rows
constexpr float KEPS = 1e-10f;

// ---- weight-fragment table (1 frag = 16x32 B-tile = 64 lanes x 16B = 1024B) ----
constexpr int FB_PX   = 0;    // 7   KT=1
constexpr int FB_HE   = 7;    // 56  KT=8 (concat px|h)
constexpr int FB_EMU  = 63;   // 4   KT=4
constexpr int FB_ESIG = 67;   // 4
constexpr int FB_HP   = 71;   // 28  KT=4
constexpr int FB_PMU  = 99;   // 4
constexpr int FB_PSIG = 103;  // 4
constexpr int FB_PZ   = 107;  // 7   KT=1
constexpr int FB_HD1  = 114;  // 56  KT=8 (concat pz|h)
constexpr int FB_HD2  = 170;  // 28  KT=4
constexpr int FB_PRB  = 198;  // 8   KT=4 (Nt=2)
constexpr int FB_GIR  = 206;  // 56  KT=8 (concat pz|px)
constexpr int FB_GIU  = 262;  // 56
constexpr int FB_GIN  = 318;  // 56
constexpr int FB_GHR  = 374;  // 28  KT=4
constexpr int FB_GHU  = 402;  // 28
constexpr int FB_GHN  = 430;  // 28
constexpr int NFRAG   = 458;  // 469 KB in d_ws

struct Params {
  const float *x,*eps,*Wpx,*bpx,*Wpz,*bpz,*Wp1,*bp1,*Wp_mu,*bp_mu,*Wp_sig,*bp_sig,
              *We1,*be1,*We_mu,*be_mu,*We_sig,*be_sig,*Wd1,*bd1,*Wd2,*bd2,*Wd3,*bd3,
              *Wih,*Whh,*bih,*bhh;
  float *out;
};

DEVFN float frcp(float x){ return __builtin_amdgcn_rcpf(x); }
DEVFN float fsigmoid(float v){ return frcp(1.f + __expf(-v)); }
DEVFN float ftanh(float v){
  float t = __expf(-2.f*fabsf(v));           // (0,1], no overflow
  float r = (1.f - t) * frcp(1.f + t);
  return copysignf(r, v);
}
DEVFN float fsoftplus(float v){
  float sp = (v > 15.f) ? v : __logf(1.f + __expf(v));
  return fmaxf(sp, 1e-6f);                   // log/rcp safety in KL tail
}

DEVFN f32x4 MFMA(bf16x8 a, bf16x8 b, f32x4 c){
  return __builtin_amdgcn_mfma_f32_16x16x32_bf16(a, b, c, 0, 0, 0);
}

// ---------------- weight prep: fp32 -> bf16 B-fragments, biases folded into K-pad slot ----------------
__global__ void prep_kernel(Params P, __bf16* FRW)
{
  const int f = blockIdx.x, l = threadIdx.x;
  const int bases[18] = {FB_PX,FB_HE,FB_EMU,FB_ESIG,FB_HP,FB_PMU,FB_PSIG,FB_PZ,FB_HD1,
                         FB_HD2,FB_PRB,FB_GIR,FB_GIU,FB_GIN,FB_GHR,FB_GHU,FB_GHN,NFRAG};
  int li = 0;
  while (f >= bases[li+1]) ++li;

  const float* W; const float* Bv; int KT, N, roff, wstr, vK, mode;
  switch (li) {
    case 0:  W=P.Wpx;    Bv=P.bpx;    KT=1; N=100; roff=0;   wstr=28;  vK=28;  mode=0; break;
    case 1:  W=P.We1;    Bv=P.be1;    KT=8; N=100; roff=0;   wstr=200; vK=100; mode=1; break;
    case 2:  W=P.We_mu;  Bv=P.be_mu;  KT=4; N=16;  roff=0;   wstr=100; vK=100; mode=0; break;
    case 3:  W=P.We_sig; Bv=P.be_sig; KT=4; N=16;  roff=0;   wstr=100; vK=100; mode=0; break;
    case 4:  W=P.Wp1;    Bv=P.bp1;    KT=4; N=100; roff=0;   wstr=100; vK=100; mode=0; break;
    case 5:  W=P.Wp_mu;  Bv=P.bp_mu;  KT=4; N=16;  roff=0;   wstr=100; vK=100; mode=0; break;
    case 6:  W=P.Wp_sig; Bv=P.bp_sig; KT=4; N=16;  roff=0;   wstr=100; vK=100; mode=0; break;
    case 7:  W=P.Wpz;    Bv=P.bpz;    KT=1; N=100; roff=0;   wstr=16;  vK=16;  mode=0; break;
    case 8:  W=P.Wd1;    Bv=P.bd1;    KT=8; N=100; roff=0;   wstr=200; vK=100; mode=1; break;
    case 9:  W=P.Wd2;    Bv=P.bd2;    KT=4; N=100; roff=0;   wstr=100; vK=100; mode=0; break;
    case 10: W=P.Wd3;    Bv=P.bd3;    KT=4; N=28;  roff=0;   wstr=100; vK=100; mode=0; break;
    case 11: W=P.Wih;    Bv=P.bih;    KT=8; N=100; roff=0;   wstr=200; vK=100; mode=1; break;
    case 12: W=P.Wih;    Bv=P.bih;    KT=8; N=100; roff=100; wstr=200; vK=100; mode=1; break;
    case 13: W=P.Wih;    Bv=P.bih;    KT=8; N=100; roff=200; wstr=200; vK=100; mode=1; break;
    case 14: W=P.Whh;    Bv=P.bhh;    KT=4; N=100; roff=0;   wstr=100; vK=100; mode=0; break;
    case 15: W=P.Whh;    Bv=P.bhh;    KT=4; N=100; roff=100; wstr=100; vK=100; mode=0; break;
    default: W=P.Whh;    Bv=P.bhh;    KT=4; N=100; roff=200; wstr=100; vK=100; mode=0; break;
  }
  const int idx = f - bases[li];
  const int nt = idx / KT, kc = idx % KT;
  const int n  = nt*16 + (l & 15);

  bf16x8 v;
  #pragma unroll
  for (int j = 0; j < 8; ++j) {
    int kk  = (mode ? (kc & 3) : kc)*32 + ((l >> 4)*8) + j;
    float w = 0.f;
    if (n < N) {
      if (mode == 0) {
        if (kk < vK)       w = W[(size_t)(roff + n)*wstr + kk];
        else if (kk == vK) w = Bv[roff + n];                      // bias in K-pad slot
      } else {
        int col = (kc < 4 ? 0 : 100) + kk;
        if (kk < 100)                    w = W[(size_t)(roff + n)*wstr + col];
        else if (kc < 4 && kk == 100)    w = Bv[roff + n];        // bias in segment-0 pad slot
      }
    }
    v[j] = (__bf16)w;
  }
  *((bf16x8*)FRW + (size_t)f*64 + l) = v;
}

// ---------------- main kernel helpers (single M-tile; R5 runtime-loop structure) ----------------
template<int NC>
DEVFN void load_afrags(bf16x8 (&af)[NC], const __bf16* A, int stride, int lane)
{
  const __bf16* p = A + (size_t)(lane & 15)*stride + ((lane >> 4)*8);
  #pragma unroll
  for (int kc = 0; kc < NC; ++kc) af[kc] = *(const bf16x8*)(p + kc*32);
}

// H-output layer: this wave does nt = sw, sw+2, ... ; relu; bias pre-folded into weights
template<int KT, int NA>
DEVFN void layerH(const bf16x8 (&af)[NA], const bf16x8* FRbase, __bf16* dst, int sw, int lane)
{
  for (int nt = sw; nt < 7; nt += 2) {
    f32x4 acc = {0.f,0.f,0.f,0.f};
    const bf16x8* wf = FRbase + (size_t)nt*KT*64 + lane;
    #pragma unroll
    for (int kc = 0; kc < KT; ++kc) acc = MFMA(af[kc], wf[kc*64], acc);
    const int col = nt*16 + (lane & 15);
    if (col < H) {
      const int rbase = (lane >> 4)*4;
      #pragma unroll
      for (int r = 0; r < 4; ++r)
        dst[(size_t)(rbase + r)*ST + col] = (__bf16)fmaxf(acc[r], 0.f);
    }
  }
}

// K-concat variant of layerH (two 4-frag A arrays)
DEVFN void layerHcat(const bf16x8 (&a0)[4], const bf16x8 (&a1)[4], const bf16x8* FRbase,
                     __bf16* dst, int sw, int lane)
{
  for (int nt = sw; nt < 7; nt += 2) {
    f32x4 acc = {0.f,0.f,0.f,0.f};
    const bf16x8* wf = FRbase + (size_t)nt*8*64 + lane;
    #pragma unroll
    for (int kc = 0; kc < 4; ++kc) acc = MFMA(a0[kc], wf[kc*64], acc);
    #pragma unroll
    for (int kc = 0; kc < 4; ++kc) acc = MFMA(a1[kc], wf[(4+kc)*64], acc);
    const int col = nt*16 + (lane & 15);
    if (col < H) {
      const int rbase = (lane >> 4)*4;
      #pragma unroll
      for (int r = 0; r < 4; ++r)
        dst[(size_t)(rbase + r)*ST + col] = (__bf16)fmaxf(acc[r], 0.f);
    }
  }
}

template<int KT>
DEVFN f32x4 head4(const bf16x8 (&af)[KT], const bf16x8* FRbase, int lane)
{
  f32x4 acc = {0.f,0.f,0.f,0.f};
  #pragma unroll
  for (int kc = 0; kc < KT; ++kc) acc = MFMA(af[kc], FRbase[kc*64 + lane], acc);
  return acc;
}

__global__ __launch_bounds__(NTH, 2) void vrnn_kernel(Params P, const __bf16* FRW)
{
  __shared__ alignas(16) __bf16 sPX[HBUF];
  __shared__ alignas(16) __bf16 sPZ[HBUF];
  __shared__ alignas(16) __bf16 sA [HBUF];   // he -> hd1
  __shared__ alignas(16) __bf16 sB [HBUF];   // hp -> hd2
  __shared__ alignas(16) __bf16 sH [HBUF];   // single-buffered h
  __shared__ alignas(16) __bf16 sZ [ROWS*XST];
  __shared__ float sred[4];

  const bf16x8* FR = (const bf16x8*)FRW;
  const int tid  = threadIdx.x;
  const int lane = tid & 63;
  const int wv   = tid >> 6;       // 0 or 1
  const int gr0  = blockIdx.x * ROWS;

  // zero-init ALL LDS, then plant bias-activation 1.0 at the K-pad column.
  for (int i = tid; i < HBUF; i += NTH) {
    sPX[i]=(__bf16)0.f; sPZ[i]=(__bf16)0.f; sA[i]=(__bf16)0.f; sB[i]=(__bf16)0.f; sH[i]=(__bf16)0.f;
  }
  for (int i = tid; i < ROWS*XST; i += NTH) sZ[i]=(__bf16)0.f;
  __syncthreads();
  if (tid < ROWS) {
    sPX[tid*ST+100]=(__bf16)1.f; sPZ[tid*ST+100]=(__bf16)1.f; sA[tid*ST+100]=(__bf16)1.f;
    sB [tid*ST+100]=(__bf16)1.f; sH [tid*ST+100]=(__bf16)1.f; sZ[tid*XST+16]=(__bf16)1.f;
  }
  __syncthreads();

  float kl = 0.f, nll = 0.f;

  for (int t = 0; t < T; ++t) {
    // ---- P1: px = relu(x Wpx^T + b) (x A-frag from global, bias-one at k=28) ; hp -> sB
    {
      const int m = lane & 15, quad = lane >> 4;
      const float* xr = P.x + ((size_t)t*B + gr0 + m)*X + quad*8;
      float4 fa = *(const float4*)xr;
      float4 fb = make_float4(0.f,0.f,0.f,0.f);
      if (quad < 3) fb = *(const float4*)(xr + 4);
      bf16x8 ax;
      ax[0]=(__bf16)fa.x; ax[1]=(__bf16)fa.y; ax[2]=(__bf16)fa.z; ax[3]=(__bf16)fa.w;
      ax[4]=(__bf16)fb.x; ax[5]=(__bf16)fb.y; ax[6]=(__bf16)fb.z; ax[7]=(__bf16)fb.w;
      if (quad == 3) ax[4] = (__bf16)1.f;    // k=28 bias slot
      bf16x8 axA[1] = {ax};
      layerH<1,1>(axA, FR + (size_t)FB_PX*64, sPX, wv, lane);
      bf16x8 ah[4]; load_afrags(ah, sH, ST, lane);
      layerH<4,4>(ah, FR + (size_t)FB_HP*64, sB, wv ^ 1, lane);
    }
    __syncthreads();   // B1

    // ---- P2: he = relu([px|h] We1^T + b) -> sA
    {
      bf16x8 a0[4]; load_afrags(a0, sPX, ST, lane);
      bf16x8 a1[4]; load_afrags(a1, sH,  ST, lane);
      layerHcat(a0, a1, FR + (size_t)FB_HE*64, sA, wv, lane);
    }
    __syncthreads();   // B2

    // ---- P3 (no barrier): BOTH waves compute all 4 Z-heads; z dup-written; KL split by reg half
    {
      bf16x8 a1[4]; load_afrags(a1, sA, ST, lane);
      bf16x8 a2[4]; load_afrags(a2, sB, ST, lane);
      f32x4 emu = head4(a1, FR + (size_t)FB_EMU*64,  lane);
      f32x4 esg = head4(a1, FR + (size_t)FB_ESIG*64, lane);
      f32x4 pmu = head4(a2, FR + (size_t)FB_PMU*64,  lane);
      f32x4 psg = head4(a2, FR + (size_t)FB_PSIG*64, lane);
      const int zi = lane & 15;
      const int rbase = (lane >> 4)*4;
      #pragma unroll
      for (int r = 0; r < 4; ++r) {
        float em = emu[r];
        float es = fsoftplus(esg[r]);
        float ev = P.eps[((size_t)t*B + gr0 + rbase + r)*Z + zi];
        sZ[(rbase + r)*XST + zi] = (__bf16)(em + __builtin_amdgcn_sqrtf(es)*ev);  // dup write
        if ((r >> 1) == wv) {   // each wave accumulates half the KL terms
          float ps = fsoftplus(psg[r]) + KEPS;
          float dm = em - pmu[r];
          float rps = frcp(ps);
          kl += 0.5f*(2.f*__logf(ps*frcp(es)) + (es*es + dm*dm)*(rps*rps) - 1.f);
        }
      }
    }
    // no barrier: each wave reads only its own sZ writes below

    // ---- P4: pz = relu(z Wpz^T + b) -> sPZ  (bias-one at z col 16)
    {
      bf16x8 az[1]; load_afrags(az, sZ, XST, lane);
      layerH<1,1>(az, FR + (size_t)FB_PZ*64, sPZ, wv ^ 1, lane);
    }
    __syncthreads();   // B4

    // ---- P5: load all A-frags; barrier; hd1 -> sA ; fused GRU -> sH (in place)
    {
      bf16x8 apz[4]; load_afrags(apz, sPZ, ST, lane);
      bf16x8 ah [4]; load_afrags(ah,  sH,  ST, lane);
      bf16x8 apx[4]; load_afrags(apx, sPX, ST, lane);
      __syncthreads(); // B5a: both waves' h/pz/px frags in regs before any sH/sA write

      layerHcat(apz, ah, FR + (size_t)FB_HD1*64, sA, wv, lane);

      for (int c = (wv ^ 1); c < 7; c += 2) {
        f32x4 gr={0.f,0.f,0.f,0.f}, gu={0.f,0.f,0.f,0.f}, gn={0.f,0.f,0.f,0.f};
        f32x4 hr={0.f,0.f,0.f,0.f}, hu={0.f,0.f,0.f,0.f}, hn={0.f,0.f,0.f,0.f};
        const bf16x8* wr = FR + (size_t)(FB_GIR + c*8)*64 + lane;
        const bf16x8* wu = FR + (size_t)(FB_GIU + c*8)*64 + lane;
        const bf16x8* wn = FR + (size_t)(FB_GIN + c*8)*64 + lane;
        #pragma unroll
        for (int kc = 0; kc < 4; ++kc) {        // gi part 1: pz (bih folded here)
          bf16x8 a = apz[kc];
          gr = MFMA(a, wr[kc*64], gr); gu = MFMA(a, wu[kc*64], gu); gn = MFMA(a, wn[kc*64], gn);
        }
        #pragma unroll
        for (int kc = 0; kc < 4; ++kc) {        // gi part 2: px
          bf16x8 a = apx[kc];
          gr = MFMA(a, wr[(4+kc)*64], gr); gu = MFMA(a, wu[(4+kc)*64], gu); gn = MFMA(a, wn[(4+kc)*64], gn);
        }
        const bf16x8* vr = FR + (size_t)(FB_GHR + c*4)*64 + lane;
        const bf16x8* vu = FR + (size_t)(FB_GHU + c*4)*64 + lane;
        const bf16x8* vn = FR + (size_t)(FB_GHN + c*4)*64 + lane;
        #pragma unroll
        for (int kc = 0; kc < 4; ++kc) {        // gh: h (bhh folded here)
          bf16x8 a = ah[kc];
          hr = MFMA(a, vr[kc*64], hr); hu = MFMA(a, vu[kc*64], hu); hn = MFMA(a, vn[kc*64], hn);
        }
        const int n = c*16 + (lane & 15);
        if (n < H) {
          const int rbase = (lane >> 4)*4;
          #pragma unroll
          for (int r = 0; r < 4; ++r) {
            float rr = fsigmoid(gr[r] + hr[r]);
            float uu = fsigmoid(gu[r] + hu[r]);
            float nn = ftanh(gn[r] + rr*hn[r]);
            float ho = (float)sH[(size_t)(rbase+r)*ST + n];   // own (row,col): exclusive
            sH[(size_t)(rbase+r)*ST + n] = (__bf16)((1.f-uu)*nn + uu*ho);
          }
        }
      }
    }
    __syncthreads();   // B5b

    // ---- P6: hd2 = relu(hd1 Wd2^T + b) : sA -> sB
    {
      bf16x8 af[4]; load_afrags(af, sA, ST, lane);
      layerH<4,4>(af, FR + (size_t)FB_HD2*64, sB, wv, lane);
    }
    __syncthreads();   // B6

    // ---- P7: logits v = hd2 Wd3^T + b ; NLL via log-sigmoid identity (wave wv does tile wv)
    {
      bf16x8 af[4]; load_afrags(af, sB, ST, lane);
      f32x4 acc = head4(af, FR + (size_t)(FB_PRB + wv*4)*64, lane);
      const int n = wv*16 + (lane & 15);
      if (n < X) {
        const int rbase = (lane >> 4)*4;
        #pragma unroll
        for (int r = 0; r < 4; ++r) {
          float v  = acc[r];
          float xv = P.x[((size_t)t*B + gr0 + rbase + r)*X + n];
          nll += fmaxf(-v, 0.f) + __logf(1.f + __expf(-fabsf(v))) + (1.f - xv)*v;
        }
      }
    }
    __syncthreads();   // B7 (protects sPX/sB overwrite next step)
  } // t

  // ---- reduce kl/nll: wave shuffle -> LDS -> one atomicAdd per block
  for (int off = 32; off > 0; off >>= 1) {
    kl  += __shfl_down(kl,  off);
    nll += __shfl_down(nll, off);
  }
  if (lane == 0) { sred[wv] = kl; sred[2 + wv] = nll; }
  __syncthreads();
  if (tid == 0) {
    atomicAdd(&P.out[0], (sred[0] + sred[1]) * (1.f/(float)B));
    atomicAdd(&P.out[1], (sred[2] + sred[3]) * (1.f/(float)B));
  }
}

} // namespace

extern "C" void kernel_launch(void* const* d_in, const int* in_sizes, int n_in,
                              void* d_out, int out_size, void* d_ws, size_t ws_size,
                              hipStream_t stream)
{
  Params p;
  const float* const* f = (const float* const*)d_in;
  p.x=f[0];    p.eps=f[1];
  p.Wpx=f[2];  p.bpx=f[3];   p.Wpz=f[4];   p.bpz=f[5];
  p.Wp1=f[6];  p.bp1=f[7];   p.Wp_mu=f[8]; p.bp_mu=f[9];
  p.Wp_sig=f[10]; p.bp_sig=f[11];
  p.We1=f[12]; p.be1=f[13];  p.We_mu=f[14]; p.be_mu=f[15];
  p.We_sig=f[16]; p.be_sig=f[17];
  p.Wd1=f[18]; p.bd1=f[19];  p.Wd2=f[20];  p.bd2=f[21];
  p.Wd3=f[22]; p.bd3=f[23];
  p.Wih=f[24]; p.Whh=f[25];  p.bih=f[26];  p.bhh=f[27];
  p.out = (float*)d_out;

  hipMemsetAsync(d_out, 0, 2*sizeof(float), stream);
  prep_kernel<<<dim3(NFRAG), dim3(64), 0, stream>>>(p, (__bf16*)d_ws);
  vrnn_kernel<<<dim3(B/ROWS), dim3(NTH), 0, stream>>>(p, (const __bf16*)d_ws);
}